// Round 2
// baseline (171.078 us; speedup 1.0000x reference)
//
#include <hip/hip_runtime.h>

#define B_ 4
#define T_ 4096
#define C_ 1024
#define H_ 64

typedef _Float16 half8  __attribute__((ext_vector_type(8)));
typedef _Float16 half4_ __attribute__((ext_vector_type(4)));
typedef float    floatx4 __attribute__((ext_vector_type(4)));

#define MFMA16(a, b, c) __builtin_amdgcn_mfma_f32_16x16x32_f16(a, b, c, 0, 0, 0)

// ---------------------------------------------------------------------------
// Kernel 1: pack W into MFMA-fragment order (lane-contiguous A-frags):
// Wt2[((mt*16 + j)*2 + f)*64 + lane]*8 + jj  <-  W[k][h'],
//   k = j*64 + f*32 + (lane>>4)*8 + jj,  h' = mt*16 + (lane&15)  (mt 0..11)
// ---------------------------------------------------------------------------
__global__ __launch_bounds__(256) void pack_w_kn(
    const float* __restrict__ Wq, const float* __restrict__ Wk,
    const float* __restrict__ Wv, _Float16* __restrict__ Wt2)
{
    const int idx  = blockIdx.x * 256 + threadIdx.x;  // 0 .. 196607
    const int mt   = idx >> 14;
    const int j    = (idx >> 10) & 15;
    const int f    = (idx >> 9) & 1;
    const int lane = (idx >> 3) & 63;
    const int jj   = idx & 7;
    const int q = lane >> 4, c = lane & 15;
    const int k  = j * 64 + f * 32 + q * 8 + jj;
    const int hp = mt * 16 + c;                       // 0..191
    const float* W = (hp < 64) ? Wq : (hp < 128) ? Wk : Wv;
    Wt2[idx] = (_Float16)W[k * H_ + (hp & 63)];
}

// ---------------------------------------------------------------------------
// Kernel 2: fused QKV projection (unchanged this round).
// ---------------------------------------------------------------------------
__global__ __launch_bounds__(512) void qkv_kn(
    const float* __restrict__ x, const _Float16* __restrict__ Wt2,
    _Float16* __restrict__ Qh, _Float16* __restrict__ Kpk,
    _Float16* __restrict__ Vpk)
{
    __shared__ _Float16 xs[2][32][72];                // 9216 B
    const int tid  = threadIdx.x;
    const int lane = tid & 63, w = tid >> 6;
    const int q    = lane >> 4, c = lane & 15;
    const int nt   = w & 1;                           // n-half (16 rows)
    const int mg   = w >> 1;                          // m-group (3 m-tiles)
    const int row0 = blockIdx.x * 32;

    const int srow = tid >> 4, scol = (tid & 15) * 4;
    const float* xg = x + (size_t)(row0 + srow) * C_ + scol;

    floatx4 acc[3];
    #pragma unroll
    for (int i = 0; i < 3; ++i) acc[i] = floatx4{0.f, 0.f, 0.f, 0.f};

    float4 g = *(const float4*)xg;                    // preload tile 0

    for (int j = 0; j < 16; ++j) {
        half4_ hv;
        hv[0] = (_Float16)g.x; hv[1] = (_Float16)g.y;
        hv[2] = (_Float16)g.z; hv[3] = (_Float16)g.w;
        *(half4_*)(&xs[j & 1][srow][scol]) = hv;
        __syncthreads();
        if (j < 15) g = *(const float4*)(xg + (j + 1) * 64);

        const _Float16* xrow = &xs[j & 1][nt * 16 + c][q * 8];
        const half8 b0 = *(const half8*)xrow;
        const half8 b1 = *(const half8*)(xrow + 32);

        half8 a[6];
        #pragma unroll
        for (int i = 0; i < 3; ++i) {
            const size_t fb = ((size_t)((mg * 3 + i) * 16 + j) * 2) * 512 + lane * 8;
            a[i * 2]     = *(const half8*)(Wt2 + fb);
            a[i * 2 + 1] = *(const half8*)(Wt2 + fb + 512);
        }
        #pragma unroll
        for (int i = 0; i < 3; ++i) {
            acc[i] = MFMA16(a[i * 2],     b0, acc[i]);
            acc[i] = MFMA16(a[i * 2 + 1], b1, acc[i]);
        }
    }

    const int row = row0 + nt * 16 + c;
    const int b = row >> 12, t4 = row & (T_ - 1);
    const int kt = t4 >> 6;
    const size_t tbase = ((size_t)b * 64 + kt) * 4096;
    const int mtk = (t4 >> 4) & 3;
    const int kk  = t4 & 63;

    #pragma unroll
    for (int i = 0; i < 3; ++i) {
        const int gi = mg * 3 + i;
        if (gi < 4) {                                 // Q row-major
            half4_ v;
            #pragma unroll
            for (int r = 0; r < 4; ++r) v[r] = (_Float16)acc[i][r];
            *(half4_*)(Qh + (size_t)row * H_ + gi * 16 + q * 4) = v;
        } else if (gi < 8) {                          // K fragment-packed
            half4_ v;
            #pragma unroll
            for (int r = 0; r < 4; ++r) v[r] = (_Float16)acc[i][r];
            const int e  = gi - 4;
            const int f  = e >> 1;
            const int qa = (e * 2 + (q >> 1)) & 3;
            *(half4_*)(Kpk + tbase + ((size_t)(mtk * 2 + f) * 64 + qa * 16 + c) * 8
                       + (q & 1) * 4) = v;
        } else {                                      // V fragment-packed
            const int mtv = gi - 8;
            const int qa = (kk >> 3) & 3, fv = kk >> 5, jv = kk & 7;
            #pragma unroll
            for (int r = 0; r < 4; ++r) {
                const int cv = q * 4 + r;
                Vpk[tbase + ((size_t)(mtv * 2 + fv) * 64 + qa * 16 + cv) * 8 + jv]
                    = (_Float16)acc[i][r];
            }
        }
    }
}

// ---------------------------------------------------------------------------
// Kernel 3: causal flash attention.  NEW this round: QBLK 16 -> 32.
// Each wave now carries TWO 16-query B-fragment pairs and two online-softmax
// states, so every 16 KB K/V tile read serves 32 queries instead of 16:
// total issued K/V load traffic halves, 532 MB -> 266 MB (the round-1
// counters put attn at ~40 us = 13.3 TB/s on 532 MB -> L3-BW-bound; the
// per-XCD working set (4 MB = full L2) can't be made resident, so shrink
// the stream instead).  8-way split-K, fragment-packed K/V loads, and the
// XCD-aware bijective remap (batch per XCD pair) are retained.
// ---------------------------------------------------------------------------
__global__ __launch_bounds__(512, 4) void attn_kn(
    const _Float16* __restrict__ Qh, const _Float16* __restrict__ Kpk,
    const _Float16* __restrict__ Vpk, float* __restrict__ out)
{
    __shared__ __align__(16) char smem[73728];
    const int lane = threadIdx.x & 63;
    const int w    = threadIdx.x >> 6;                // 0..7
    const int q    = lane >> 4, c = lane & 15;

    // --- XCD-aware (b, t32) decode: bijective over 512 blocks -------------
    const int bid  = blockIdx.x;
    const int xcd  = bid & 7;                         // HW round-robin XCD id
    const int slot = bid >> 3;                        // 0..63 within XCD
    const int b    = xcd >> 1;                        // XCD pair <-> batch
    const int t32  = 127 - ((slot << 1) | (xcd & 1)); // heavy tiles first
    // ----------------------------------------------------------------------

    const int row0 = t32 * 32;
    const int grow = b * T_ + row0;
    const int nk   = (t32 >> 1) + 1;                  // 64-key tiles (last=diag)

    // wave-private P region: 2 buffers x 2 q-groups x [16 q][72] halfs
    _Float16* Pw = (_Float16*)smem + w * 4608;

    // Q B-frags for the two 16-query groups, pre-scaled by (1/8)*log2(e)
    const _Float16 qs = (_Float16)0.18033688f;
    half8 bq0[2], bq1[2];
    #pragma unroll
    for (int g = 0; g < 2; ++g) {
        const _Float16* qb = Qh + (size_t)(grow + g * 16 + c) * H_;
        bq0[g] = *(const half8*)(qb + q * 8);
        bq1[g] = *(const half8*)(qb + 32 + q * 8);
        bq0[g] *= qs; bq1[g] *= qs;
    }

    floatx4 o[4][2];
    #pragma unroll
    for (int i = 0; i < 4; ++i)
        #pragma unroll
        for (int g = 0; g < 2; ++g) o[i][g] = floatx4{0.f, 0.f, 0.f, 0.f};
    float m[2] = {-3.0e38f, -3.0e38f}, l[2] = {0.f, 0.f};

    for (int kt = w; kt < nk; kt += 8) {
        const int kb = kt * 64;
        const _Float16* Kt = Kpk + ((size_t)b * 64 + kt) * 4096;
        const _Float16* Vt = Vpk + ((size_t)b * 64 + kt) * 4096;
        half8 a0[4], a1[4];

        // K-frags: lane-contiguous packed loads
        #pragma unroll
        for (int mt = 0; mt < 4; ++mt) {
            a0[mt] = *(const half8*)(Kt + ((size_t)(mt * 2)     * 64 + lane) * 8);
            a1[mt] = *(const half8*)(Kt + ((size_t)(mt * 2 + 1) * 64 + lane) * 8);
        }
        floatx4 s[4][2];
        #pragma unroll
        for (int mt = 0; mt < 4; ++mt)
            #pragma unroll
            for (int g = 0; g < 2; ++g) {
                floatx4 z = floatx4{0.f, 0.f, 0.f, 0.f};
                z = MFMA16(a0[mt], bq0[g], z);
                s[mt][g] = MFMA16(a1[mt], bq1[g], z);
            }
        // V-frags issued now; latency hides behind softmax
        #pragma unroll
        for (int mt = 0; mt < 4; ++mt) {
            a0[mt] = *(const half8*)(Vt + ((size_t)(mt * 2)     * 64 + lane) * 8);
            a1[mt] = *(const half8*)(Vt + ((size_t)(mt * 2 + 1) * 64 + lane) * 8);
        }

        if (kt == nk - 1) {                           // causal mask (diag tile)
            #pragma unroll
            for (int mt = 0; mt < 4; ++mt)
                #pragma unroll
                for (int g = 0; g < 2; ++g)
                    #pragma unroll
                    for (int r = 0; r < 4; ++r)
                        if (kb + mt * 16 + q * 4 + r > row0 + g * 16 + c)
                            s[mt][g][r] = -3.0e38f;
        }

        // online softmax per q-group; lane holds 16 scores of one q-row/group
        _Float16* Pb = Pw + ((kt >> 3) & 1) * 2304;
        #pragma unroll
        for (int g = 0; g < 2; ++g) {
            float mx = s[0][g][0];
            #pragma unroll
            for (int mt = 0; mt < 4; ++mt)
                #pragma unroll
                for (int r = 0; r < 4; ++r) mx = fmaxf(mx, s[mt][g][r]);
            mx = fmaxf(mx, __shfl_xor(mx, 16, 64));
            mx = fmaxf(mx, __shfl_xor(mx, 32, 64));
            const float mn    = fmaxf(m[g], mx);
            const float alpha = exp2f(m[g] - mn);
            _Float16* pl = Pb + g * 1152 + c * 72;
            float sl = 0.f;
            #pragma unroll
            for (int mt = 0; mt < 4; ++mt) {
                half4_ ph;
                #pragma unroll
                for (int r = 0; r < 4; ++r) {
                    const float e = exp2f(s[mt][g][r] - mn);
                    sl += e;
                    ph[r] = (_Float16)e;
                }
                *(half4_*)(pl + mt * 16 + q * 4) = ph;
            }
            sl += __shfl_xor(sl, 16, 64);
            sl += __shfl_xor(sl, 32, 64);
            l[g] = l[g] * alpha + sl;
            m[g] = mn;
            #pragma unroll
            for (int mt = 0; mt < 4; ++mt) o[mt][g] *= alpha;
        }

        // reload P as B-frags, accumulate O^T += V^T · P^T
        half8 bp0[2], bp1[2];
        #pragma unroll
        for (int g = 0; g < 2; ++g) {
            const _Float16* pl = Pb + g * 1152 + c * 72;
            bp0[g] = *(const half8*)(pl + q * 8);
            bp1[g] = *(const half8*)(pl + 32 + q * 8);
        }
        #pragma unroll
        for (int mt = 0; mt < 4; ++mt)
            #pragma unroll
            for (int g = 0; g < 2; ++g) {
                o[mt][g] = MFMA16(a0[mt], bp0[g], o[mt][g]);
                o[mt][g] = MFMA16(a1[mt], bp1[g], o[mt][g]);
            }
    }

    // ---- flash combine across the 8 waves (overlay LDS after sync) ----
    __syncthreads();
    float* Ol = (float*)smem;                         // [8][2176] (pad 17)
    float* Ml = (float*)(smem + 69632);               // [8][32]
    float* Ll = (float*)(smem + 70656);               // [8][32]
    if (q == 0) { Ml[w * 32 + c] = m[0]; Ml[w * 32 + 16 + c] = m[1]; }
    __syncthreads();
    float M0 = Ml[c], M1 = Ml[16 + c];
    #pragma unroll
    for (int w2 = 1; w2 < 8; ++w2) {
        M0 = fmaxf(M0, Ml[w2 * 32 + c]);
        M1 = fmaxf(M1, Ml[w2 * 32 + 16 + c]);
    }
    const float alpha0 = exp2f(m[0] - M0);            // 0 for empty waves
    const float alpha1 = exp2f(m[1] - M1);
    if (q == 0) { Ll[w * 32 + c] = l[0] * alpha0; Ll[w * 32 + 16 + c] = l[1] * alpha1; }
    #pragma unroll
    for (int mt = 0; mt < 4; ++mt)
        #pragma unroll
        for (int r = 0; r < 4; ++r) {
            Ol[w * 2176 + (mt * 16 + q * 4 + r) * 17 + c]        = o[mt][0][r] * alpha0;
            Ol[w * 2176 + (64 + mt * 16 + q * 4 + r) * 17 + c]   = o[mt][1][r] * alpha1;
        }
    __syncthreads();

    const int g  = w & 1;                             // output q-group
    const int h0 = (w >> 1) * 16 + q * 4;             // output h slice
    float L = 0.f;
    #pragma unroll
    for (int w2 = 0; w2 < 8; ++w2) L += Ll[w2 * 32 + g * 16 + c];
    const float inv = 1.f / L;
    floatx4 st = floatx4{0.f, 0.f, 0.f, 0.f};
    #pragma unroll
    for (int w2 = 0; w2 < 8; ++w2)
        #pragma unroll
        for (int r = 0; r < 4; ++r)
            st[r] += Ol[w2 * 2176 + (g * 64 + h0 + r) * 17 + c];
    st *= inv;
    *(floatx4*)(out + (size_t)(grow + g * 16 + c) * H_ + h0) = st;
}

extern "C" void kernel_launch(void* const* d_in, const int* in_sizes, int n_in,
                              void* d_out, int out_size, void* d_ws, size_t ws_size,
                              hipStream_t stream) {
    const float* x  = (const float*)d_in[0];
    const float* Wq = (const float*)d_in[1];
    const float* Wk = (const float*)d_in[2];
    const float* Wv = (const float*)d_in[3];
    float* out = (float*)d_out;

    _Float16* ws = (_Float16*)d_ws;
    _Float16* Wt2 = ws;                               //   192*1024 = 196608
    _Float16* Qh  = ws + 196608;                      // 16384*64  = 1048576
    _Float16* Kpk = Qh + 1048576;                     // [4][64][4096]
    _Float16* Vpk = Kpk + 1048576;                    // [4][64][4096]

    hipLaunchKernelGGL(pack_w_kn, dim3(768), dim3(256), 0, stream, Wq, Wk, Wv, Wt2);
    hipLaunchKernelGGL(qkv_kn, dim3((B_ * T_) / 32), dim3(512), 0, stream,
                       x, Wt2, Qh, Kpk, Vpk);
    hipLaunchKernelGGL(attn_kn, dim3(512), dim3(512), 0, stream,
                       Qh, Kpk, Vpk, out);
}

// Round 5
// 165.519 us; speedup vs baseline: 1.0336x; 1.0336x over previous
//
#include <hip/hip_runtime.h>

#define B_ 4
#define T_ 4096
#define C_ 1024
#define H_ 64

typedef _Float16 half8  __attribute__((ext_vector_type(8)));
typedef _Float16 half4_ __attribute__((ext_vector_type(4)));
typedef float    floatx4 __attribute__((ext_vector_type(4)));

#define MFMA16(a, b, c)  __builtin_amdgcn_mfma_f32_16x16x32_f16(a, b, c, 0, 0, 0)
#define MFMA16K(a, b, c) __builtin_amdgcn_mfma_f32_16x16x16f16(a, b, c, 0, 0, 0)
#define LO4(v) __builtin_shufflevector(v, v, 0, 1, 2, 3)
#define HI4(v) __builtin_shufflevector(v, v, 4, 5, 6, 7)

// ---------------------------------------------------------------------------
// Kernel 1: pack W into MFMA-fragment order (lane-contiguous A-frags).
// ---------------------------------------------------------------------------
__global__ __launch_bounds__(256) void pack_w_kn(
    const float* __restrict__ Wq, const float* __restrict__ Wk,
    const float* __restrict__ Wv, _Float16* __restrict__ Wt2)
{
    const int idx  = blockIdx.x * 256 + threadIdx.x;  // 0 .. 196607
    const int mt   = idx >> 14;
    const int j    = (idx >> 10) & 15;
    const int f    = (idx >> 9) & 1;
    const int lane = (idx >> 3) & 63;
    const int jj   = idx & 7;
    const int q = lane >> 4, c = lane & 15;
    const int k  = j * 64 + f * 32 + q * 8 + jj;
    const int hp = mt * 16 + c;                       // 0..191
    const float* W = (hp < 64) ? Wq : (hp < 128) ? Wk : Wv;
    Wt2[idx] = (_Float16)W[k * H_ + (hp & 63)];
}

// ---------------------------------------------------------------------------
// Kernel 2: fused QKV projection.  Vpk is written in 16x16x16 A-frag order
// (key chunks of 16) so attn's PV can consume the QK^T C-fragment directly
// as a 16x16x16 B-frag with ZERO data movement for P.
//   Vpk[b][kt]: for element (h, key):  mt=h>>4, cv=h&15, f2=key>>5,
//   h4=(key>>4)&1, qa2=(key>>2)&3, i2=key&3 at
//   (((mt*2+f2)*64 + qa2*16 + cv)*8 + h4*4 + i2)
// ---------------------------------------------------------------------------
__global__ __launch_bounds__(512) void qkv_kn(
    const float* __restrict__ x, const _Float16* __restrict__ Wt2,
    _Float16* __restrict__ Qh, _Float16* __restrict__ Kpk,
    _Float16* __restrict__ Vpk)
{
    __shared__ _Float16 xs[2][32][72];                // 9216 B
    const int tid  = threadIdx.x;
    const int lane = tid & 63, w = tid >> 6;
    const int q    = lane >> 4, c = lane & 15;
    const int nt   = w & 1;                           // n-half (16 rows)
    const int mg   = w >> 1;                          // m-group (3 m-tiles)
    const int row0 = blockIdx.x * 32;

    const int srow = tid >> 4, scol = (tid & 15) * 4;
    const float* xg = x + (size_t)(row0 + srow) * C_ + scol;

    floatx4 acc[3];
    #pragma unroll
    for (int i = 0; i < 3; ++i) acc[i] = floatx4{0.f, 0.f, 0.f, 0.f};

    float4 g = *(const float4*)xg;                    // preload tile 0

    for (int j = 0; j < 16; ++j) {
        half4_ hv;
        hv[0] = (_Float16)g.x; hv[1] = (_Float16)g.y;
        hv[2] = (_Float16)g.z; hv[3] = (_Float16)g.w;
        *(half4_*)(&xs[j & 1][srow][scol]) = hv;
        __syncthreads();
        if (j < 15) g = *(const float4*)(xg + (j + 1) * 64);

        const _Float16* xrow = &xs[j & 1][nt * 16 + c][q * 8];
        const half8 b0 = *(const half8*)xrow;
        const half8 b1 = *(const half8*)(xrow + 32);

        half8 a[6];
        #pragma unroll
        for (int i = 0; i < 3; ++i) {
            const size_t fb = ((size_t)((mg * 3 + i) * 16 + j) * 2) * 512 + lane * 8;
            a[i * 2]     = *(const half8*)(Wt2 + fb);
            a[i * 2 + 1] = *(const half8*)(Wt2 + fb + 512);
        }
        #pragma unroll
        for (int i = 0; i < 3; ++i) {
            acc[i] = MFMA16(a[i * 2],     b0, acc[i]);
            acc[i] = MFMA16(a[i * 2 + 1], b1, acc[i]);
        }
    }

    const int row = row0 + nt * 16 + c;
    const int b = row >> 12, t4 = row & (T_ - 1);
    const int kt = t4 >> 6;
    const size_t tbase = ((size_t)b * 64 + kt) * 4096;
    const int mtk = (t4 >> 4) & 3;
    const int kk  = t4 & 63;

    #pragma unroll
    for (int i = 0; i < 3; ++i) {
        const int gi = mg * 3 + i;
        if (gi < 4) {                                 // Q row-major
            half4_ v;
            #pragma unroll
            for (int r = 0; r < 4; ++r) v[r] = (_Float16)acc[i][r];
            *(half4_*)(Qh + (size_t)row * H_ + gi * 16 + q * 4) = v;
        } else if (gi < 8) {                          // K fragment-packed (16x16x32 A-frag)
            half4_ v;
            #pragma unroll
            for (int r = 0; r < 4; ++r) v[r] = (_Float16)acc[i][r];
            const int e  = gi - 4;
            const int f  = e >> 1;
            const int qa = (e * 2 + (q >> 1)) & 3;
            *(half4_*)(Kpk + tbase + ((size_t)(mtk * 2 + f) * 64 + qa * 16 + c) * 8
                       + (q & 1) * 4) = v;
        } else {                                      // V 16x16x16 A-frag packed
            const int mtv = gi - 8;
            const int qa2 = (kk >> 2) & 3;
            const int h4  = (kk >> 4) & 1;
            const int f2  = kk >> 5;
            const int i2  = kk & 3;
            #pragma unroll
            for (int r = 0; r < 4; ++r) {
                const int cv = q * 4 + r;             // h & 15
                Vpk[tbase + ((size_t)(mtv * 2 + f2) * 64 + qa2 * 16 + cv) * 8
                    + h4 * 4 + i2] = (_Float16)acc[i][r];
            }
        }
    }
}

// ---------------------------------------------------------------------------
// Kernel 3: causal flash attention, QBLK=32, 8-way in-block split-K.
//  (a) PV via v_mfma_f32_16x16x16_f16: QK^T C-frag (lane: P[key=mt*16+q*4+r]
//      [qrow=c]) IS the 16x16x16 B-frag for key-chunk mt.  P never leaves
//      registers -> no P LDS, no bank conflicts, no dbuf.  V sub-frags are
//      extracted with __builtin_shufflevector (register-level; NO address-of
//      on register arrays -> no scratch).
//  (b) LDS 36864 (combine in 2 passes over q-groups).
//  (c) Balanced folded block map: slot<32 -> heavy t32=127-(2s+e), slot>=32
//      -> light t32=2(s-32)+e.  Every CU's two blocks sum to ~65 tiles.
//      Heavy-first retained, batch per XCD pair.
// ---------------------------------------------------------------------------
__global__ __launch_bounds__(512, 4) void attn_kn(
    const _Float16* __restrict__ Qh, const _Float16* __restrict__ Kpk,
    const _Float16* __restrict__ Vpk, float* __restrict__ out)
{
    __shared__ __align__(16) char smem[36864];
    const int lane = threadIdx.x & 63;
    const int w    = threadIdx.x >> 6;                // 0..7
    const int q    = lane >> 4, c = lane & 15;

    // --- XCD-aware balanced (b, t32) decode: bijective over 512 blocks ----
    const int bid  = blockIdx.x;
    const int xcd  = bid & 7;                         // HW round-robin XCD id
    const int slot = bid >> 3;                        // 0..63 within XCD
    const int b    = xcd >> 1;                        // XCD pair <-> batch
    const int e    = xcd & 1;
    const int t32  = (slot < 32) ? (127 - (2 * slot + e))
                                 : (2 * (slot - 32) + e);
    // ----------------------------------------------------------------------

    const int row0 = t32 * 32;
    const int grow = b * T_ + row0;
    const int nk   = (t32 >> 1) + 1;                  // 64-key tiles (last=diag)

    // Q B-frags for the two 16-query groups, pre-scaled by (1/8)*log2(e)
    const _Float16 qs = (_Float16)0.18033688f;
    half8 bq0[2], bq1[2];
    #pragma unroll
    for (int g = 0; g < 2; ++g) {
        const _Float16* qb = Qh + (size_t)(grow + g * 16 + c) * H_;
        bq0[g] = *(const half8*)(qb + q * 8);
        bq1[g] = *(const half8*)(qb + 32 + q * 8);
        bq0[g] *= qs; bq1[g] *= qs;
    }

    floatx4 o[4][2];
    #pragma unroll
    for (int i = 0; i < 4; ++i)
        #pragma unroll
        for (int g = 0; g < 2; ++g) o[i][g] = floatx4{0.f, 0.f, 0.f, 0.f};
    float m[2] = {-3.0e38f, -3.0e38f}, l[2] = {0.f, 0.f};

    for (int kt = w; kt < nk; kt += 8) {
        const int kb = kt * 64;
        const _Float16* Kt = Kpk + ((size_t)b * 64 + kt) * 4096;
        const _Float16* Vt = Vpk + ((size_t)b * 64 + kt) * 4096;
        half8 a0[4], a1[4];

        // K-frags: lane-contiguous packed loads
        #pragma unroll
        for (int mt = 0; mt < 4; ++mt) {
            a0[mt] = *(const half8*)(Kt + ((size_t)(mt * 2)     * 64 + lane) * 8);
            a1[mt] = *(const half8*)(Kt + ((size_t)(mt * 2 + 1) * 64 + lane) * 8);
        }
        floatx4 s[4][2];
        #pragma unroll
        for (int mt = 0; mt < 4; ++mt)
            #pragma unroll
            for (int g = 0; g < 2; ++g) {
                floatx4 z = floatx4{0.f, 0.f, 0.f, 0.f};
                z = MFMA16(a0[mt], bq0[g], z);
                s[mt][g] = MFMA16(a1[mt], bq1[g], z);
            }
        // V-frags issued now; latency hides behind softmax
        #pragma unroll
        for (int mt = 0; mt < 4; ++mt) {
            a0[mt] = *(const half8*)(Vt + ((size_t)(mt * 2)     * 64 + lane) * 8);
            a1[mt] = *(const half8*)(Vt + ((size_t)(mt * 2 + 1) * 64 + lane) * 8);
        }

        if (kt == nk - 1) {                           // causal mask (diag tile)
            #pragma unroll
            for (int mt = 0; mt < 4; ++mt)
                #pragma unroll
                for (int g = 0; g < 2; ++g)
                    #pragma unroll
                    for (int r = 0; r < 4; ++r)
                        if (kb + mt * 16 + q * 4 + r > row0 + g * 16 + c)
                            s[mt][g][r] = -3.0e38f;
        }

        // online softmax per q-group; P stays in registers as 16x16x16 B-frags
        half4_ ph[2][4];
        #pragma unroll
        for (int g = 0; g < 2; ++g) {
            float mx = s[0][g][0];
            #pragma unroll
            for (int mt = 0; mt < 4; ++mt)
                #pragma unroll
                for (int r = 0; r < 4; ++r) mx = fmaxf(mx, s[mt][g][r]);
            mx = fmaxf(mx, __shfl_xor(mx, 16, 64));
            mx = fmaxf(mx, __shfl_xor(mx, 32, 64));
            const float mn    = fmaxf(m[g], mx);
            const float alpha = exp2f(m[g] - mn);
            float sl = 0.f;
            #pragma unroll
            for (int mt = 0; mt < 4; ++mt)
                #pragma unroll
                for (int r = 0; r < 4; ++r) {
                    const float ev = exp2f(s[mt][g][r] - mn);
                    sl += ev;
                    ph[g][mt][r] = (_Float16)ev;
                }
            sl += __shfl_xor(sl, 16, 64);
            sl += __shfl_xor(sl, 32, 64);
            l[g] = l[g] * alpha + sl;
            m[g] = mn;
            #pragma unroll
            for (int mt = 0; mt < 4; ++mt) o[mt][g] *= alpha;
        }

        // O^T += V^T · P^T as 4 key-chunk 16x16x16 MFMAs per o-tile
        #pragma unroll
        for (int mt = 0; mt < 4; ++mt) {
            const half4_ v0 = LO4(a0[mt]);            // key chunk 0 (keys  0..15)
            const half4_ v1 = HI4(a0[mt]);            // key chunk 1 (keys 16..31)
            const half4_ v2 = LO4(a1[mt]);            // key chunk 2 (keys 32..47)
            const half4_ v3 = HI4(a1[mt]);            // key chunk 3 (keys 48..63)
            #pragma unroll
            for (int g = 0; g < 2; ++g) {
                o[mt][g] = MFMA16K(v0, ph[g][0], o[mt][g]);
                o[mt][g] = MFMA16K(v1, ph[g][1], o[mt][g]);
                o[mt][g] = MFMA16K(v2, ph[g][2], o[mt][g]);
                o[mt][g] = MFMA16K(v3, ph[g][3], o[mt][g]);
            }
        }
    }

    // ---- flash combine across the 8 waves: 2 passes over q-groups --------
    float* Ol = (float*)smem;                         // [8][1088] (pad 17)
    float* Ml = (float*)(smem + 34816);               // [8][32]
    float* Ll = (float*)(smem + 35840);               // [8][32]
    __syncthreads();
    if (q == 0) { Ml[w * 32 + c] = m[0]; Ml[w * 32 + 16 + c] = m[1]; }
    __syncthreads();
    float M0 = Ml[c], M1 = Ml[16 + c];
    #pragma unroll
    for (int w2 = 1; w2 < 8; ++w2) {
        M0 = fmaxf(M0, Ml[w2 * 32 + c]);
        M1 = fmaxf(M1, Ml[w2 * 32 + 16 + c]);
    }
    const float alpha0 = exp2f(m[0] - M0);            // 0 for empty waves
    const float alpha1 = exp2f(m[1] - M1);
    if (q == 0) { Ll[w * 32 + c] = l[0] * alpha0; Ll[w * 32 + 16 + c] = l[1] * alpha1; }

    const int h0 = w * 8 + q * 2;                     // this thread's h slice
    #pragma unroll
    for (int gp = 0; gp < 2; ++gp) {
        const float a = gp ? alpha1 : alpha0;
        #pragma unroll
        for (int mt = 0; mt < 4; ++mt)
            #pragma unroll
            for (int r = 0; r < 4; ++r)
                Ol[w * 1088 + (mt * 16 + q * 4 + r) * 17 + c] = o[mt][gp][r] * a;
        __syncthreads();
        float L = 0.f;
        #pragma unroll
        for (int w2 = 0; w2 < 8; ++w2) L += Ll[w2 * 32 + gp * 16 + c];
        const float inv = 1.f / L;
        float ox = 0.f, oy = 0.f;
        #pragma unroll
        for (int w2 = 0; w2 < 8; ++w2) {
            ox += Ol[w2 * 1088 + h0 * 17 + c];
            oy += Ol[w2 * 1088 + (h0 + 1) * 17 + c];
        }
        float2 st; st.x = ox * inv; st.y = oy * inv;
        *(float2*)(out + (size_t)(grow + gp * 16 + c) * H_ + h0) = st;
        if (gp == 0) __syncthreads();                 // before pass-1 overwrite
    }
}

extern "C" void kernel_launch(void* const* d_in, const int* in_sizes, int n_in,
                              void* d_out, int out_size, void* d_ws, size_t ws_size,
                              hipStream_t stream) {
    const float* x  = (const float*)d_in[0];
    const float* Wq = (const float*)d_in[1];
    const float* Wk = (const float*)d_in[2];
    const float* Wv = (const float*)d_in[3];
    float* out = (float*)d_out;

    _Float16* ws = (_Float16*)d_ws;
    _Float16* Wt2 = ws;                               //   192*1024 = 196608
    _Float16* Qh  = ws + 196608;                      // 16384*64  = 1048576
    _Float16* Kpk = Qh + 1048576;                     // [4][64][4096]
    _Float16* Vpk = Kpk + 1048576;                    // [4][64][4096]

    hipLaunchKernelGGL(pack_w_kn, dim3(768), dim3(256), 0, stream, Wq, Wk, Wv, Wt2);
    hipLaunchKernelGGL(qkv_kn, dim3((B_ * T_) / 32), dim3(512), 0, stream,
                       x, Wt2, Qh, Kpk, Vpk);
    hipLaunchKernelGGL(attn_kn, dim3(512), dim3(512), 0, stream,
                       Qh, Kpk, Vpk, out);
}